// Round 3
// baseline (469.329 us; speedup 1.0000x reference)
//
#include <hip/hip_runtime.h>

#define B  8
#define NV 4096
#define NE 32768
#define D  128
#define KE 512   // De + 2*Dv + Du
#define KN 384   // Dep + Dv + Du
#define KG 384   // Dep + Dvp + Du

using short8    = __attribute__((ext_vector_type(8))) short;
using f32x4     = __attribute__((ext_vector_type(4))) float;
using ushort4_t = __attribute__((ext_vector_type(4))) unsigned short;

__device__ inline unsigned short f2bf(float f) {
    unsigned u = __builtin_bit_cast(unsigned, f);
    u += 0x7FFFu + ((u >> 16) & 1u);          // RNE
    return (unsigned short)(u >> 16);
}

// swizzled bf16x4 store into LDS tile (XOR bits 4-6 of byte addr with row&7)
__device__ inline void store_bf4(unsigned short* base, int ldus, int row, int j, float4 v) {
    const int byte = (j * 2) ^ ((row & 7) << 4);
    ushort4_t p = { f2bf(v.x), f2bf(v.y), f2bf(v.z), f2bf(v.w) };
    *(ushort4_t*)(base + row * ldus + (byte >> 1)) = p;
}

// ---------------------------------------------------------------------------
// weight prep: Wt[n][k] = bf16(W[k][n])
// ---------------------------------------------------------------------------
__global__ __launch_bounds__(256) void prep_weights(
    const float* __restrict__ We, const float* __restrict__ Wn,
    unsigned short* __restrict__ WtE, unsigned short* __restrict__ WtN)
{
    const int idx = blockIdx.x * 256 + threadIdx.x;       // 0 .. 65535
    {   // edge: 128 x 512
        const int n = idx >> 9, k = idx & 511;
        WtE[idx] = f2bf(We[(size_t)k * D + n]);
    }
    if (idx < 128 * KN) {                                  // node: 128 x 384
        const int n = idx / KN, k = idx % KN;
        WtN[idx] = f2bf(Wn[(size_t)k * D + n]);
    }
}

// ---------------------------------------------------------------------------
// CSR build: histogram -> per-batch exclusive scan -> scatter edge ids
// ---------------------------------------------------------------------------
__global__ __launch_bounds__(256) void hist_kernel(
    const int* __restrict__ edge_rs, const int* __restrict__ edge_masks,
    int* __restrict__ cnt)
{
    const int idx = blockIdx.x * 256 + threadIdx.x;       // over B*NE
    if (edge_masks[idx]) {
        const int b = idx >> 15;                          // NE = 2^15
        const int r = edge_rs[2 * idx];                   // receiver
        atomicAdd(cnt + b * NV + r, 1);
    }
}

__global__ __launch_bounds__(1024) void scan_kernel(
    const int* __restrict__ cnt, int* __restrict__ off, int* __restrict__ cur)
{
    const int b = blockIdx.x, t = threadIdx.x;
    __shared__ int part[1024];
    int4 c = *(const int4*)(cnt + b * NV + t * 4);
    const int s0 = c.x, s1 = s0 + c.y, s2 = s1 + c.z, s3 = s2 + c.w;
    part[t] = s3;
    __syncthreads();
    #pragma unroll
    for (int d = 1; d < 1024; d <<= 1) {
        const int v = (t >= d) ? part[t - d] : 0;
        __syncthreads();
        part[t] += v;
        __syncthreads();
    }
    const int base = part[t] - s3;                        // exclusive
    int* o = off + b * (NV + 1) + t * 4;
    o[0] = base; o[1] = base + s0; o[2] = base + s1; o[3] = base + s2;
    int4 cc = { base, base + s0, base + s1, base + s2 };
    *(int4*)(cur + b * NV + t * 4) = cc;
    if (t == 1023) off[b * (NV + 1) + NV] = part[1023];
}

__global__ __launch_bounds__(256) void scatter_kernel(
    const int* __restrict__ edge_rs, const int* __restrict__ edge_masks,
    int* __restrict__ cur, int* __restrict__ elist)
{
    const int idx = blockIdx.x * 256 + threadIdx.x;
    if (edge_masks[idx]) {
        const int b = idx >> 15;
        const int e = idx & (NE - 1);
        const int r = edge_rs[2 * idx];
        const int pos = atomicAdd(cur + b * NV + r, 1);
        elist[b * NE + pos] = e;
    }
}

// ---------------------------------------------------------------------------
// Edge block (MFMA, swapped operands): 64 edges/block, 512 thr = 8 waves,
// wave wv -> cols [16*wv, 16*wv+16). Lane holds 4 consecutive cols of one row.
// ---------------------------------------------------------------------------
__global__ __launch_bounds__(512, 4) void edge_kernel(
    const float* __restrict__ nodes,
    const float* __restrict__ edges,
    const float* __restrict__ gu,
    const int*   __restrict__ edge_rs,
    const unsigned short* __restrict__ WtE,   // (128,512) bf16, n-major
    const float* __restrict__ b_edge,
    float* __restrict__ edges_p,
    float* __restrict__ e2u)
{
    __shared__ unsigned short Ash[64 * KE];   // 64 KB swizzled bf16 concat tile

    const int b   = blockIdx.y;
    const int e0  = blockIdx.x * 64;
    const int tid = threadIdx.x;
    const int tx  = tid & 31;
    const int ty  = tid >> 5;                 // 0..15
    const int j0  = tx * 4;

    const float4 uv = *(const float4*)(gu + (size_t)b * D + j0);
    #pragma unroll
    for (int i = 0; i < 4; ++i) {
        const int    row = ty + 16 * i;
        const size_t eb  = (size_t)b * NE + e0 + row;
        const int2   rs  = ((const int2*)edge_rs)[eb];
        const float4 ev  = *(const float4*)(edges + eb * (size_t)D + j0);
        const float4 rv  = *(const float4*)(nodes + ((size_t)b * NV + rs.x) * D + j0);
        const float4 sv  = *(const float4*)(nodes + ((size_t)b * NV + rs.y) * D + j0);
        store_bf4(Ash, KE, row,   0 + j0, ev);
        store_bf4(Ash, KE, row, 128 + j0, rv);
        store_bf4(Ash, KE, row, 256 + j0, sv);
        store_bf4(Ash, KE, row, 384 + j0, uv);
    }
    __syncthreads();

    const int lane = tid & 63;
    const int wv   = tid >> 6;                // 0..7 -> col tile
    const int lc   = lane & 15;
    const int lg   = lane >> 4;
    const int c0   = wv * 16 + lg * 4;        // first of this lane's 4 cols

    f32x4 acc[4] = {};
    #pragma unroll 4
    for (int ks = 0; ks < KE / 32; ++ks) {
        const int kk = ks * 32 + lg * 8;
        const short8 wfr = *(const short8*)(WtE + (size_t)(wv * 16 + lc) * KE + kk);
        #pragma unroll
        for (int mt = 0; mt < 4; ++mt) {
            const int row  = mt * 16 + lc;
            const int byte = (kk * 2) ^ ((row & 7) << 4);
            const short8 afr = *(const short8*)(Ash + row * KE + (byte >> 1));
            acc[mt] = __builtin_amdgcn_mfma_f32_16x16x32_bf16(wfr, afr, acc[mt], 0, 0, 0);
        }
    }

    // epilogue: bias+relu, float4 stores, e2u column sums
    const float4 bb = *(const float4*)(b_edge + c0);
    float sx = 0.f, sy = 0.f, sz = 0.f, sw = 0.f;
    #pragma unroll
    for (int mt = 0; mt < 4; ++mt) {
        const int row = mt * 16 + lc;
        float4 o;
        o.x = fmaxf(acc[mt][0] + bb.x, 0.f);
        o.y = fmaxf(acc[mt][1] + bb.y, 0.f);
        o.z = fmaxf(acc[mt][2] + bb.z, 0.f);
        o.w = fmaxf(acc[mt][3] + bb.w, 0.f);
        *(float4*)(edges_p + ((size_t)b * NE + e0 + row) * D + c0) = o;
        sx += o.x; sy += o.y; sz += o.z; sw += o.w;
    }
    #pragma unroll
    for (int m = 1; m < 16; m <<= 1) {
        sx += __shfl_xor(sx, m);
        sy += __shfl_xor(sy, m);
        sz += __shfl_xor(sz, m);
        sw += __shfl_xor(sw, m);
    }
    if (lc == 0) {
        float* dst = e2u + (size_t)b * D + c0;
        atomicAdd(dst + 0, sx);
        atomicAdd(dst + 1, sy);
        atomicAdd(dst + 2, sz);
        atomicAdd(dst + 3, sw);
    }
}

// ---------------------------------------------------------------------------
// Node block (MFMA, swapped operands): 64 nodes/block, gather e2v via CSR.
// ---------------------------------------------------------------------------
__global__ __launch_bounds__(512, 4) void node_kernel(
    const float* __restrict__ nodes,
    const float* __restrict__ gu,
    const float* __restrict__ edges_p,
    const int*   __restrict__ off,            // (B, NV+1)
    const int*   __restrict__ elist,          // (B, NE)
    const unsigned short* __restrict__ WtN,   // (128,384) bf16, n-major
    const float* __restrict__ b_node,
    float* __restrict__ nodes_p,
    float* __restrict__ v2u)
{
    __shared__ unsigned short Ash[64 * KN];   // 48 KB

    const int b   = blockIdx.y;
    const int n0  = blockIdx.x * 64;
    const int tid = threadIdx.x;
    const int tx  = tid & 31;
    const int ty  = tid >> 5;
    const int j0  = tx * 4;

    const float4 uv = *(const float4*)(gu + (size_t)b * D + j0);
    #pragma unroll
    for (int i = 0; i < 4; ++i) {
        const int row = ty + 16 * i;
        const int v   = n0 + row;
        const int p0  = off[b * (NV + 1) + v];
        const int p1  = off[b * (NV + 1) + v + 1];
        float ax = 0.f, ay = 0.f, az = 0.f, aw = 0.f;
        for (int p = p0; p < p1; ++p) {
            const int e = elist[b * NE + p];
            const float4 x = *(const float4*)(edges_p + ((size_t)b * NE + e) * D + j0);
            ax += x.x; ay += x.y; az += x.z; aw += x.w;
        }
        const size_t nb = (size_t)b * NV + v;
        const float4 nv = *(const float4*)(nodes + nb * (size_t)D + j0);
        store_bf4(Ash, KN, row,   0 + j0, make_float4(ax, ay, az, aw));
        store_bf4(Ash, KN, row, 128 + j0, nv);
        store_bf4(Ash, KN, row, 256 + j0, uv);
    }
    __syncthreads();

    const int lane = tid & 63;
    const int wv   = tid >> 6;
    const int lc   = lane & 15;
    const int lg   = lane >> 4;
    const int c0   = wv * 16 + lg * 4;

    f32x4 acc[4] = {};
    #pragma unroll 4
    for (int ks = 0; ks < KN / 32; ++ks) {
        const int kk = ks * 32 + lg * 8;
        const short8 wfr = *(const short8*)(WtN + (size_t)(wv * 16 + lc) * KN + kk);
        #pragma unroll
        for (int mt = 0; mt < 4; ++mt) {
            const int row  = mt * 16 + lc;
            const int byte = (kk * 2) ^ ((row & 7) << 4);
            const short8 afr = *(const short8*)(Ash + row * KN + (byte >> 1));
            acc[mt] = __builtin_amdgcn_mfma_f32_16x16x32_bf16(wfr, afr, acc[mt], 0, 0, 0);
        }
    }

    const float4 bb = *(const float4*)(b_node + c0);
    float sx = 0.f, sy = 0.f, sz = 0.f, sw = 0.f;
    #pragma unroll
    for (int mt = 0; mt < 4; ++mt) {
        const int row = mt * 16 + lc;
        float4 o;
        o.x = fmaxf(acc[mt][0] + bb.x, 0.f);
        o.y = fmaxf(acc[mt][1] + bb.y, 0.f);
        o.z = fmaxf(acc[mt][2] + bb.z, 0.f);
        o.w = fmaxf(acc[mt][3] + bb.w, 0.f);
        *(float4*)(nodes_p + ((size_t)b * NV + n0 + row) * D + c0) = o;
        sx += o.x; sy += o.y; sz += o.z; sw += o.w;
    }
    #pragma unroll
    for (int m = 1; m < 16; m <<= 1) {
        sx += __shfl_xor(sx, m);
        sy += __shfl_xor(sy, m);
        sz += __shfl_xor(sz, m);
        sw += __shfl_xor(sw, m);
    }
    if (lc == 0) {
        float* dst = v2u + (size_t)b * D + c0;
        atomicAdd(dst + 0, sx);
        atomicAdd(dst + 1, sy);
        atomicAdd(dst + 2, sz);
        atomicAdd(dst + 3, sw);
    }
}

// ---------------------------------------------------------------------------
// Global block: relu(concat(e2u, v2u, u) @ W_g + b_g)  (fp32, tiny)
// ---------------------------------------------------------------------------
__global__ __launch_bounds__(128) void glob_kernel(
    const float* __restrict__ e2u,
    const float* __restrict__ v2u,
    const float* __restrict__ gu,
    const float* __restrict__ W_glob,
    const float* __restrict__ b_glob,
    float* __restrict__ glob_p)
{
    __shared__ float gin[KG];
    const int b = blockIdx.x;
    const int j = threadIdx.x;

    gin[j      ] = e2u[(size_t)b * D + j];
    gin[j + 128] = v2u[(size_t)b * D + j];
    gin[j + 256] = gu [(size_t)b * D + j];
    __syncthreads();

    float acc = b_glob[j];
    #pragma unroll 4
    for (int k = 0; k < KG; ++k)
        acc += gin[k] * W_glob[(size_t)k * D + j];
    glob_p[(size_t)b * D + j] = fmaxf(acc, 0.f);
}

// ---------------------------------------------------------------------------
extern "C" void kernel_launch(void* const* d_in, const int* in_sizes, int n_in,
                              void* d_out, int out_size, void* d_ws, size_t ws_size,
                              hipStream_t stream) {
    const float* nodes      = (const float*)d_in[0];
    const float* edges      = (const float*)d_in[1];
    const float* gu         = (const float*)d_in[2];
    const int*   edge_rs    = (const int*)d_in[3];
    const int*   edge_masks = (const int*)d_in[4];
    const float* W_edge     = (const float*)d_in[5];
    const float* b_edge     = (const float*)d_in[6];
    const float* W_node     = (const float*)d_in[7];
    const float* b_node     = (const float*)d_in[8];
    const float* W_glob     = (const float*)d_in[9];
    const float* b_glob     = (const float*)d_in[10];

    float* out     = (float*)d_out;
    float* nodes_p = out;
    float* edges_p = out + (size_t)B * NV * D;
    float* glob_p  = edges_p + (size_t)B * NE * D;

    // workspace layout
    int*   cnt   = (int*)d_ws;                       // B*NV
    int*   off   = cnt + (size_t)B * NV;             // B*(NV+1)
    int*   cur   = off + (size_t)B * (NV + 1);       // B*NV
    int*   elist = cur + (size_t)B * NV;             // B*NE
    float* e2u   = (float*)(elist + (size_t)B * NE); // B*D
    float* v2u   = e2u + (size_t)B * D;              // B*D
    unsigned short* WtE = (unsigned short*)(v2u + (size_t)B * D);  // 128*512
    unsigned short* WtN = WtE + 128 * KE;                          // 128*384

    hipMemsetAsync(cnt, 0, (size_t)B * NV * sizeof(int), stream);
    hipMemsetAsync(e2u, 0, 2 * (size_t)B * D * sizeof(float), stream);

    prep_weights<<<(128 * KE) / 256, 256, 0, stream>>>(W_edge, W_node, WtE, WtN);
    hist_kernel<<<(B * NE) / 256, 256, 0, stream>>>(edge_rs, edge_masks, cnt);
    scan_kernel<<<B, 1024, 0, stream>>>(cnt, off, cur);
    scatter_kernel<<<(B * NE) / 256, 256, 0, stream>>>(edge_rs, edge_masks, cur, elist);

    dim3 eg(NE / 64, B);
    edge_kernel<<<eg, 512, 0, stream>>>(nodes, edges, gu, edge_rs,
                                        WtE, b_edge, edges_p, e2u);
    dim3 ng(NV / 64, B);
    node_kernel<<<ng, 512, 0, stream>>>(nodes, gu, edges_p, off, elist,
                                        WtN, b_node, nodes_p, v2u);
    glob_kernel<<<B, 128, 0, stream>>>(e2u, v2u, gu, W_glob, b_glob, glob_p);
}

// Round 4
// 255.090 us; speedup vs baseline: 1.8399x; 1.8399x over previous
//
#include <hip/hip_runtime.h>

#define B  8
#define NV 4096
#define NE 32768
#define D  128
#define KE 512   // De + 2*Dv + Du
#define KN 384   // Dep + Vv + Du
#define KG 384   // Dep + Dvp + Du

using short8    = __attribute__((ext_vector_type(8))) short;
using f32x4     = __attribute__((ext_vector_type(4))) float;
using ushort4_t = __attribute__((ext_vector_type(4))) unsigned short;

__device__ inline unsigned short f2bf(float f) {
    unsigned u = __builtin_bit_cast(unsigned, f);
    u += 0x7FFFu + ((u >> 16) & 1u);          // RNE
    return (unsigned short)(u >> 16);
}

// swizzled bf16x4 store into LDS tile (XOR bits 4-6 of byte addr with row&7)
__device__ inline void store_bf4(unsigned short* base, int ldus, int row, int j, float4 v) {
    const int byte = (j * 2) ^ ((row & 7) << 4);
    ushort4_t p = { f2bf(v.x), f2bf(v.y), f2bf(v.z), f2bf(v.w) };
    *(ushort4_t*)(base + row * ldus + (byte >> 1)) = p;
}

// ---------------------------------------------------------------------------
// weight prep: Wt[n][k] = bf16(W[k][n])
// ---------------------------------------------------------------------------
__global__ __launch_bounds__(256) void prep_weights(
    const float* __restrict__ We, const float* __restrict__ Wn,
    unsigned short* __restrict__ WtE, unsigned short* __restrict__ WtN)
{
    const int idx = blockIdx.x * 256 + threadIdx.x;       // 0 .. 65535
    {   // edge: 128 x 512
        const int n = idx >> 9, k = idx & 511;
        WtE[idx] = f2bf(We[(size_t)k * D + n]);
    }
    if (idx < 128 * KN) {                                  // node: 128 x 384
        const int n = idx / KN, k = idx % KN;
        WtN[idx] = f2bf(Wn[(size_t)k * D + n]);
    }
}

// ---------------------------------------------------------------------------
// CSR build: histogram -> per-batch exclusive scan -> scatter edge ids
// ---------------------------------------------------------------------------
__global__ __launch_bounds__(256) void hist_kernel(
    const int* __restrict__ edge_rs, const int* __restrict__ edge_masks,
    int* __restrict__ cnt)
{
    const int idx = blockIdx.x * 256 + threadIdx.x;       // over B*NE
    if (edge_masks[idx]) {
        const int b = idx >> 15;                          // NE = 2^15
        const int r = edge_rs[2 * idx];                   // receiver
        atomicAdd(cnt + b * NV + r, 1);
    }
}

__global__ __launch_bounds__(1024) void scan_kernel(
    const int* __restrict__ cnt, int* __restrict__ off, int* __restrict__ cur)
{
    const int b = blockIdx.x, t = threadIdx.x;
    __shared__ int part[1024];
    int4 c = *(const int4*)(cnt + b * NV + t * 4);
    const int s0 = c.x, s1 = s0 + c.y, s2 = s1 + c.z, s3 = s2 + c.w;
    part[t] = s3;
    __syncthreads();
    #pragma unroll
    for (int d = 1; d < 1024; d <<= 1) {
        const int v = (t >= d) ? part[t - d] : 0;
        __syncthreads();
        part[t] += v;
        __syncthreads();
    }
    const int base = part[t] - s3;                        // exclusive
    int* o = off + b * (NV + 1) + t * 4;
    o[0] = base; o[1] = base + s0; o[2] = base + s1; o[3] = base + s2;
    int4 cc = { base, base + s0, base + s1, base + s2 };
    *(int4*)(cur + b * NV + t * 4) = cc;
    if (t == 1023) off[b * (NV + 1) + NV] = part[1023];
}

__global__ __launch_bounds__(256) void scatter_kernel(
    const int* __restrict__ edge_rs, const int* __restrict__ edge_masks,
    int* __restrict__ cur, int* __restrict__ elist)
{
    const int idx = blockIdx.x * 256 + threadIdx.x;
    if (edge_masks[idx]) {
        const int b = idx >> 15;
        const int e = idx & (NE - 1);
        const int r = edge_rs[2 * idx];
        const int pos = atomicAdd(cur + b * NV + r, 1);
        elist[b * NE + pos] = e;
    }
}

// ---------------------------------------------------------------------------
// Edge block (MFMA): 64 edges/block, 256 thr = 4 waves, wave wv -> cols
// [32wv, 32wv+32). Wave's W panel (2 nt x 16 ks) held in 128 VGPRs.
// K-loop is pure LDS + MFMA.
// ---------------------------------------------------------------------------
__global__ __launch_bounds__(256, 2) void edge_kernel(
    const float* __restrict__ nodes,
    const float* __restrict__ edges,
    const float* __restrict__ gu,
    const int*   __restrict__ edge_rs,
    const unsigned short* __restrict__ WtE,   // (128,512) bf16, n-major
    const float* __restrict__ b_edge,
    float* __restrict__ edges_p,
    float* __restrict__ e2u)
{
    __shared__ unsigned short Ash[64 * KE];   // 64 KB swizzled bf16 concat tile

    const int b   = blockIdx.y;
    const int e0  = blockIdx.x * 64;
    const int tid = threadIdx.x;
    const int tx  = tid & 31;
    const int ty  = tid >> 5;                 // 0..7
    const int j0  = tx * 4;

    const int lane = tid & 63;
    const int wv   = tid >> 6;                // 0..3 -> col tile base 32*wv
    const int lc   = lane & 15;
    const int lg   = lane >> 4;

    // ---- hoist the wave's W panel into registers (L2-resident reads) ----
    short8 wreg[16][2];
    #pragma unroll
    for (int ks = 0; ks < 16; ++ks)
        #pragma unroll
        for (int nt = 0; nt < 2; ++nt)
            wreg[ks][nt] = *(const short8*)(WtE + (size_t)(wv * 32 + nt * 16 + lc) * KE
                                                + ks * 32 + lg * 8);

    // ---- stage concat tile into LDS (gather + cvt), coalesced float4 ----
    const float4 uv = *(const float4*)(gu + (size_t)b * D + j0);
    #pragma unroll
    for (int i = 0; i < 8; ++i) {
        const int    row = ty + 8 * i;
        const size_t eb  = (size_t)b * NE + e0 + row;
        const int2   rs  = ((const int2*)edge_rs)[eb];
        const float4 ev  = *(const float4*)(edges + eb * (size_t)D + j0);
        const float4 rv  = *(const float4*)(nodes + ((size_t)b * NV + rs.x) * D + j0);
        const float4 sv  = *(const float4*)(nodes + ((size_t)b * NV + rs.y) * D + j0);
        store_bf4(Ash, KE, row,   0 + j0, ev);
        store_bf4(Ash, KE, row, 128 + j0, rv);
        store_bf4(Ash, KE, row, 256 + j0, sv);
        store_bf4(Ash, KE, row, 384 + j0, uv);
    }
    __syncthreads();

    // ---- K-loop: pure ds_read_b128 + MFMA, fully unrolled ----
    f32x4 acc[4][2] = {};
    #pragma unroll
    for (int ks = 0; ks < 16; ++ks) {
        const int kk = ks * 32 + lg * 8;
        #pragma unroll
        for (int mt = 0; mt < 4; ++mt) {
            const int row  = mt * 16 + lc;
            const int byte = (kk * 2) ^ ((row & 7) << 4);
            const short8 afr = *(const short8*)(Ash + row * KE + (byte >> 1));
            acc[mt][0] = __builtin_amdgcn_mfma_f32_16x16x32_bf16(afr, wreg[ks][0], acc[mt][0], 0, 0, 0);
            acc[mt][1] = __builtin_amdgcn_mfma_f32_16x16x32_bf16(afr, wreg[ks][1], acc[mt][1], 0, 0, 0);
        }
    }

    // ---- epilogue: bias + relu, store, e2u column sums ----
    #pragma unroll
    for (int nt = 0; nt < 2; ++nt) {
        const int col  = wv * 32 + nt * 16 + lc;
        const float bias = b_edge[col];
        float csum = 0.f;
        #pragma unroll
        for (int mt = 0; mt < 4; ++mt) {
            const int rbase = mt * 16 + lg * 4;
            #pragma unroll
            for (int r = 0; r < 4; ++r) {
                const int row = rbase + r;
                const float v = fmaxf(acc[mt][nt][r] + bias, 0.f);
                edges_p[((size_t)b * NE + e0 + row) * D + col] = v;
                csum += v;
            }
        }
        csum += __shfl_xor(csum, 16);
        csum += __shfl_xor(csum, 32);
        if (lg == 0) atomicAdd(e2u + (size_t)b * D + col, csum);
    }
}

// ---------------------------------------------------------------------------
// Node block (MFMA): 64 nodes/block, CSR gather of edges_p, W panel in regs.
// ---------------------------------------------------------------------------
__global__ __launch_bounds__(256, 2) void node_kernel(
    const float* __restrict__ nodes,
    const float* __restrict__ gu,
    const float* __restrict__ edges_p,
    const int*   __restrict__ off,            // (B, NV+1)
    const int*   __restrict__ elist,          // (B, NE)
    const unsigned short* __restrict__ WtN,   // (128,384) bf16, n-major
    const float* __restrict__ b_node,
    float* __restrict__ nodes_p,
    float* __restrict__ v2u)
{
    __shared__ unsigned short Ash[64 * KN];   // 48 KB

    const int b   = blockIdx.y;
    const int n0  = blockIdx.x * 64;
    const int tid = threadIdx.x;
    const int tx  = tid & 31;
    const int ty  = tid >> 5;
    const int j0  = tx * 4;

    const int lane = tid & 63;
    const int wv   = tid >> 6;
    const int lc   = lane & 15;
    const int lg   = lane >> 4;

    short8 wreg[12][2];
    #pragma unroll
    for (int ks = 0; ks < 12; ++ks)
        #pragma unroll
        for (int nt = 0; nt < 2; ++nt)
            wreg[ks][nt] = *(const short8*)(WtN + (size_t)(wv * 32 + nt * 16 + lc) * KN
                                                + ks * 32 + lg * 8);

    const float4 uv = *(const float4*)(gu + (size_t)b * D + j0);
    #pragma unroll
    for (int i = 0; i < 8; ++i) {
        const int row = ty + 8 * i;
        const int v   = n0 + row;
        const int p0  = off[b * (NV + 1) + v];
        const int p1  = off[b * (NV + 1) + v + 1];
        float ax = 0.f, ay = 0.f, az = 0.f, aw = 0.f;
        for (int p = p0; p < p1; ++p) {
            const int e = elist[b * NE + p];
            const float4 x = *(const float4*)(edges_p + ((size_t)b * NE + e) * D + j0);
            ax += x.x; ay += x.y; az += x.z; aw += x.w;
        }
        const size_t nb = (size_t)b * NV + v;
        const float4 nv = *(const float4*)(nodes + nb * (size_t)D + j0);
        store_bf4(Ash, KN, row,   0 + j0, make_float4(ax, ay, az, aw));
        store_bf4(Ash, KN, row, 128 + j0, nv);
        store_bf4(Ash, KN, row, 256 + j0, uv);
    }
    __syncthreads();

    f32x4 acc[4][2] = {};
    #pragma unroll
    for (int ks = 0; ks < 12; ++ks) {
        const int kk = ks * 32 + lg * 8;
        #pragma unroll
        for (int mt = 0; mt < 4; ++mt) {
            const int row  = mt * 16 + lc;
            const int byte = (kk * 2) ^ ((row & 7) << 4);
            const short8 afr = *(const short8*)(Ash + row * KN + (byte >> 1));
            acc[mt][0] = __builtin_amdgcn_mfma_f32_16x16x32_bf16(afr, wreg[ks][0], acc[mt][0], 0, 0, 0);
            acc[mt][1] = __builtin_amdgcn_mfma_f32_16x16x32_bf16(afr, wreg[ks][1], acc[mt][1], 0, 0, 0);
        }
    }

    #pragma unroll
    for (int nt = 0; nt < 2; ++nt) {
        const int col  = wv * 32 + nt * 16 + lc;
        const float bias = b_node[col];
        float csum = 0.f;
        #pragma unroll
        for (int mt = 0; mt < 4; ++mt) {
            const int rbase = mt * 16 + lg * 4;
            #pragma unroll
            for (int r = 0; r < 4; ++r) {
                const int row = rbase + r;
                const float v = fmaxf(acc[mt][nt][r] + bias, 0.f);
                nodes_p[((size_t)b * NV + n0 + row) * D + col] = v;
                csum += v;
            }
        }
        csum += __shfl_xor(csum, 16);
        csum += __shfl_xor(csum, 32);
        if (lg == 0) atomicAdd(v2u + (size_t)b * D + col, csum);
    }
}

// ---------------------------------------------------------------------------
// Global block: relu(concat(e2u, v2u, u) @ W_g + b_g)  (fp32, tiny)
// ---------------------------------------------------------------------------
__global__ __launch_bounds__(128) void glob_kernel(
    const float* __restrict__ e2u,
    const float* __restrict__ v2u,
    const float* __restrict__ gu,
    const float* __restrict__ W_glob,
    const float* __restrict__ b_glob,
    float* __restrict__ glob_p)
{
    __shared__ float gin[KG];
    const int b = blockIdx.x;
    const int j = threadIdx.x;

    gin[j      ] = e2u[(size_t)b * D + j];
    gin[j + 128] = v2u[(size_t)b * D + j];
    gin[j + 256] = gu [(size_t)b * D + j];
    __syncthreads();

    float acc = b_glob[j];
    #pragma unroll 4
    for (int k = 0; k < KG; ++k)
        acc += gin[k] * W_glob[(size_t)k * D + j];
    glob_p[(size_t)b * D + j] = fmaxf(acc, 0.f);
}

// ---------------------------------------------------------------------------
extern "C" void kernel_launch(void* const* d_in, const int* in_sizes, int n_in,
                              void* d_out, int out_size, void* d_ws, size_t ws_size,
                              hipStream_t stream) {
    const float* nodes      = (const float*)d_in[0];
    const float* edges      = (const float*)d_in[1];
    const float* gu         = (const float*)d_in[2];
    const int*   edge_rs    = (const int*)d_in[3];
    const int*   edge_masks = (const int*)d_in[4];
    const float* W_edge     = (const float*)d_in[5];
    const float* b_edge     = (const float*)d_in[6];
    const float* W_node     = (const float*)d_in[7];
    const float* b_node     = (const float*)d_in[8];
    const float* W_glob     = (const float*)d_in[9];
    const float* b_glob     = (const float*)d_in[10];

    float* out     = (float*)d_out;
    float* nodes_p = out;
    float* edges_p = out + (size_t)B * NV * D;
    float* glob_p  = edges_p + (size_t)B * NE * D;

    // workspace layout
    int*   cnt   = (int*)d_ws;                       // B*NV
    int*   off   = cnt + (size_t)B * NV;             // B*(NV+1)
    int*   cur   = off + (size_t)B * (NV + 1);       // B*NV
    int*   elist = cur + (size_t)B * NV;             // B*NE
    float* e2u   = (float*)(elist + (size_t)B * NE); // B*D
    float* v2u   = e2u + (size_t)B * D;              // B*D
    unsigned short* WtE = (unsigned short*)(v2u + (size_t)B * D);  // 128*512
    unsigned short* WtN = WtE + 128 * KE;                          // 128*384

    hipMemsetAsync(cnt, 0, (size_t)B * NV * sizeof(int), stream);
    hipMemsetAsync(e2u, 0, 2 * (size_t)B * D * sizeof(float), stream);

    prep_weights<<<(128 * KE) / 256, 256, 0, stream>>>(W_edge, W_node, WtE, WtN);
    hist_kernel<<<(B * NE) / 256, 256, 0, stream>>>(edge_rs, edge_masks, cnt);
    scan_kernel<<<B, 1024, 0, stream>>>(cnt, off, cur);
    scatter_kernel<<<(B * NE) / 256, 256, 0, stream>>>(edge_rs, edge_masks, cur, elist);

    dim3 eg(NE / 64, B);
    edge_kernel<<<eg, 256, 0, stream>>>(nodes, edges, gu, edge_rs,
                                        WtE, b_edge, edges_p, e2u);
    dim3 ng(NV / 64, B);
    node_kernel<<<ng, 256, 0, stream>>>(nodes, gu, edges_p, off, elist,
                                        WtN, b_node, nodes_p, v2u);
    glob_kernel<<<B, 128, 0, stream>>>(e2u, v2u, gu, W_glob, b_glob, glob_p);
}